// Round 4
// baseline (137.759 us; speedup 1.0000x reference)
//
#include <hip/hip_runtime.h>

// out[b,o,i,j] = sum_c | sum_{ti,tj<=8} K[o,0,ti,tj] * x[b,c,(i+5-ti)&127,(j+5-tj)&127] |
// B=8 C=16 H=W=128 O=32. MFMA im2col formulation (verified R3):
//   per (b,c): D[m][o] = sum_k A[m][k]*Bk[k][o], k = ti*16+tj (tj pad 16, ti pad 10, K=160)
//   A[m][k] = x[i+5-ti][j+5-tj], j = 8*m + phase.  acc += |D| over c.
// LDS: column-reversed bf16 halo rows; m-tile = 16 px at stride 8 -> 16B-aligned
// ds_read_b128; odd phases extracted via v_alignbit from a 32B window.
// R4: stage 4 channels per barrier pair (barriers 32 -> 8), unroll compute over
//     4 channels for MFMA ILP. LDS 11.5 KB.

typedef __attribute__((ext_vector_type(8)))  short  short8;
typedef __attribute__((ext_vector_type(4)))  float  float4v;
typedef __attribute__((ext_vector_type(4)))  unsigned int uint4v;

#define NROW 10
#define NCC  144            // bf16 per LDS row = 288 B row stride
#define CHG  4              // channels per staging group
#define CHSZ (NROW * NCC)   // 1440 bf16 = 2880 B per channel

__device__ __forceinline__ unsigned short f2bf(float f) {
    union { float f; unsigned int u; } a; a.f = f;
    unsigned int u = a.u;
    u += 0x7fffu + ((u >> 16) & 1u);   // RNE
    return (unsigned short)(u >> 16);
}

// frag = 8 bf16 starting at byte offset 4*q_ + 2*odd_ within window wnd[0..7]
#define MFMA_PHASE(q_, odd_, Bf_, Dv_)                                       \
    {                                                                        \
        uint4v fr;                                                           \
        if (odd_) {                                                          \
            fr.x = (unsigned int)((((unsigned long long)wnd[(q_)+1] << 32) | wnd[(q_)+0]) >> 16); \
            fr.y = (unsigned int)((((unsigned long long)wnd[(q_)+2] << 32) | wnd[(q_)+1]) >> 16); \
            fr.z = (unsigned int)((((unsigned long long)wnd[(q_)+3] << 32) | wnd[(q_)+2]) >> 16); \
            fr.w = (unsigned int)((((unsigned long long)wnd[(q_)+4] << 32) | wnd[(q_)+3]) >> 16); \
        } else {                                                             \
            fr.x = wnd[(q_)+0]; fr.y = wnd[(q_)+1];                          \
            fr.z = wnd[(q_)+2]; fr.w = wnd[(q_)+3];                          \
        }                                                                    \
        short8 af = __builtin_bit_cast(short8, fr);                          \
        Dv_ = __builtin_amdgcn_mfma_f32_16x16x32_bf16(af, Bf_, Dv_, 0, 0, 0); \
    }

__global__ __launch_bounds__(256, 4)
void optical_conv_69698729279498(const float* __restrict__ x,
                                 const float* __restrict__ kern,
                                 float* __restrict__ out) {
    __shared__ __align__(16) unsigned short ldsb[CHG * CHSZ];  // 11520 B

    const int tid = threadIdx.x;
    const int l   = tid & 63;
    const int w   = tid >> 6;       // wave 0..3
    const int h   = w & 1;          // phase-half: p' = 4h + pp
    const int oh  = w >> 1;         // o-half
    const int i   = blockIdx.x;     // output row 0..127
    const int b   = blockIdx.y;     // batch 0..7

    const int lk   = l & 15;        // A m-index / B,D o-index
    const int g    = (l >> 4) & 1;  // tj half for A
    const int hi32 = l >> 5;        // ti parity within chunk for A
    const int g2   = l >> 4;        // quad 0..3
    const int o    = oh * 16 + lk;

    // ---- B fragments: Bk[k=ti*16+tj][o], zeros for ti>8 or tj>8 (once per block)
    short8 Bf[5];
#pragma unroll
    for (int ck = 0; ck < 5; ++ck) {
        const int ti  = 2 * ck + (g2 >> 1);
        const int tj0 = (g2 & 1) * 8;
        unsigned int pk[4];
#pragma unroll
        for (int ee = 0; ee < 4; ++ee) {
            int tj_a = tj0 + 2 * ee, tj_b = tj_a + 1;
            float va = (ti <= 8 && tj_a <= 8) ? kern[o * 1296 + ti * 9 + tj_a] : 0.f;
            float vb = (ti <= 8 && tj_b <= 8) ? kern[o * 1296 + ti * 9 + tj_b] : 0.f;
            pk[ee] = (unsigned int)f2bf(va) | ((unsigned int)f2bf(vb) << 16);
        }
        uint4v bv; bv.x = pk[0]; bv.y = pk[1]; bv.z = pk[2]; bv.w = pk[3];
        Bf[ck] = __builtin_bit_cast(short8, bv);
    }

    float4v acc[4];
#pragma unroll
    for (int pp = 0; pp < 4; ++pp) acc[pp] = (float4v){0.f, 0.f, 0.f, 0.f};

    for (int g4 = 0; g4 < 4; ++g4) {
        __syncthreads();  // protect LDS from previous group's readers
        // ---- stage 4 channels x 10 x 144 bf16, column-reversed, circular wrap
#pragma unroll
        for (int ch = 0; ch < CHG; ++ch) {
            const float* xp = x + (((size_t)(b * 16 + g4 * CHG + ch)) << 14);
#pragma unroll
            for (int k = 0; k < 3; ++k) {
                int s = tid + 256 * k;             // dword slot in [0,720)
                if (s < 720) {
                    int rr  = s / 72;
                    int ccd = s - rr * 72;
                    int cc  = 2 * ccd;
                    int xrow = (i - 4 + rr) & 127;
                    int c0 = (132 - cc) & 127;
                    int c1 = (131 - cc) & 127;
                    float v0 = xp[(xrow << 7) + c0];
                    float v1 = xp[(xrow << 7) + c1];
                    unsigned int pk2 =
                        (unsigned int)f2bf(v0) | ((unsigned int)f2bf(v1) << 16);
                    *(unsigned int*)&ldsb[ch * CHSZ + rr * NCC + cc] = pk2;
                }
            }
        }
        __syncthreads();

        // ---- compute: 4 channels x 5 chunks x 4 MFMA, fully unrolled
#pragma unroll
        for (int ch4 = 0; ch4 < CHG; ++ch4) {
            const unsigned short* lb = ldsb + ch4 * CHSZ;
            float4v D[4];
#pragma unroll
            for (int pp = 0; pp < 4; ++pp) D[pp] = (float4v){0.f, 0.f, 0.f, 0.f};

#pragma unroll
            for (int ck = 0; ck < 5; ++ck) {
                const int ti = 2 * ck + hi32;
                const int r  = 9 - ti;
                // 32 B window: 16 taps for this (row, ti), 16B-aligned
                const char* base = (const char*)lb + (r * 288 + 240 - 16 * lk + 16 * g);
                uint4v w0 = *(const uint4v*)base;
                uint4v w1 = *(const uint4v*)(base + 16);
                unsigned int wnd[8] = {w0.x, w0.y, w0.z, w0.w, w1.x, w1.y, w1.z, w1.w};
                if (h == 0) {               // phases 0..3 -> byte offsets 14,12,10,8
                    MFMA_PHASE(3, 1, Bf[ck], D[0]);
                    MFMA_PHASE(3, 0, Bf[ck], D[1]);
                    MFMA_PHASE(2, 1, Bf[ck], D[2]);
                    MFMA_PHASE(2, 0, Bf[ck], D[3]);
                } else {                    // phases 4..7 -> byte offsets 6,4,2,0
                    MFMA_PHASE(1, 1, Bf[ck], D[0]);
                    MFMA_PHASE(1, 0, Bf[ck], D[1]);
                    MFMA_PHASE(0, 1, Bf[ck], D[2]);
                    MFMA_PHASE(0, 0, Bf[ck], D[3]);
                }
            }
#pragma unroll
            for (int pp = 0; pp < 4; ++pp)
#pragma unroll
                for (int e = 0; e < 4; ++e) acc[pp][e] += fabsf(D[pp][e]);
        }
    }

    // ---- epilogue: lane holds o = oh*16+lk, pixels j = 32*g2 + 8*e + p'
    float* ob = out + ((((size_t)(b * 32 + o)) * 128 + i) << 7);
#pragma unroll
    for (int pp = 0; pp < 4; ++pp) {
        const int pprime = 4 * h + pp;
#pragma unroll
        for (int e = 0; e < 4; ++e)
            ob[32 * g2 + 8 * e + pprime] = acc[pp][e];
    }
}

extern "C" void kernel_launch(void* const* d_in, const int* in_sizes, int n_in,
                              void* d_out, int out_size, void* d_ws, size_t ws_size,
                              hipStream_t stream) {
    const float* x = (const float*)d_in[0];      // [8,16,128,128]
    const float* kern = (const float*)d_in[1];   // [32,16,9,9]
    float* out = (float*)d_out;                  // [8,32,128,128]
    dim3 block(256);
    dim3 grid(128, 8);   // one block per (output row, batch); writes all 32 o
    hipLaunchKernelGGL(optical_conv_69698729279498, grid, block, 0, stream,
                       x, kern, out);
}

// Round 5
// 97.195 us; speedup vs baseline: 1.4174x; 1.4174x over previous
//
#include <hip/hip_runtime.h>

// out[b,o,i,j] = sum_c | sum_{ti,tj<=8} K[o,0,ti,tj] * x[b,c,(i+5-ti)&127,(j+5-tj)&127] |
// B=8 C=16 H=W=128 O=32. MFMA im2col (verified R3 math):
//   per (b,c): D[m][o] = sum_k A[m][k]*Bk[k][o], k = ti*16+tj (tj pad 16, ti pad 10)
//   A[m][k] = x[i+5-ti][j+5-tj], j = 8*m + phase.  acc += |D| over c.
// LDS: column-reversed bf16 halo rows; m-tile = 16 px at stride 8 -> 16B-aligned
// ds_read_b128; odd phases via v_alignbit from a 32B window. Conflict-free (R3: 0).
// R5: stage ALL 16 channels once (50.7 KB LDS), ONE barrier per kernel.
//     2 output rows/block, 512 threads (8 waves), grid 512 = 2 blocks/CU fully
//     resident, zero tail. Staging loads issued in two register-bounded groups
//     (13+12 slots/thread) to stay under the launch_bounds(512,4) 128-reg cap
//     (R4's spill lesson: WRITE_SIZE must stay at exactly 16 MB).

typedef __attribute__((ext_vector_type(8)))  short  short8;
typedef __attribute__((ext_vector_type(4)))  float  float4v;
typedef __attribute__((ext_vector_type(4)))  unsigned int uint4v;

#define NROW 11                  // halo rows for 2 output rows: i0-4 .. i0+6
#define NCC  144                 // bf16 per LDS row = 288 B row stride
#define CHSZ (NROW * NCC)        // 1584 bf16 per channel
#define NSLOT (16 * NROW * 72)   // 12672 dword slots total

__device__ __forceinline__ unsigned short f2bf(float f) {
    union { float f; unsigned int u; } a; a.f = f;
    unsigned int u = a.u;
    u += 0x7fffu + ((u >> 16) & 1u);   // RNE
    return (unsigned short)(u >> 16);
}

// frag = 8 bf16 starting at byte offset 4*q_ + 2*odd_ within window wnd[0..7]
#define MFMA_PHASE(q_, odd_, Bf_, Dv_)                                       \
    {                                                                        \
        uint4v fr;                                                           \
        if (odd_) {                                                          \
            fr.x = (unsigned int)((((unsigned long long)wnd[(q_)+1] << 32) | wnd[(q_)+0]) >> 16); \
            fr.y = (unsigned int)((((unsigned long long)wnd[(q_)+2] << 32) | wnd[(q_)+1]) >> 16); \
            fr.z = (unsigned int)((((unsigned long long)wnd[(q_)+3] << 32) | wnd[(q_)+2]) >> 16); \
            fr.w = (unsigned int)((((unsigned long long)wnd[(q_)+4] << 32) | wnd[(q_)+3]) >> 16); \
        } else {                                                             \
            fr.x = wnd[(q_)+0]; fr.y = wnd[(q_)+1];                          \
            fr.z = wnd[(q_)+2]; fr.w = wnd[(q_)+3];                          \
        }                                                                    \
        short8 af = __builtin_bit_cast(short8, fr);                          \
        Dv_ = __builtin_amdgcn_mfma_f32_16x16x32_bf16(af, Bf_, Dv_, 0, 0, 0); \
    }

// decode dword slot s -> loads + LDS dword index
#define LOAD_SLOT(s_, v0_, v1_, ad_)                                         \
    {                                                                        \
        int ch  = (s_) / 792;                                                \
        int rem = (s_) - 792 * ch;                                           \
        int rr  = rem / 72;                                                  \
        int ccd = rem - 72 * rr;                                             \
        int cc  = 2 * ccd;                                                   \
        int xrow = (i0 - 4 + rr) & 127;                                      \
        const float* xp = xb + (ch << 14) + (xrow << 7);                     \
        v0_ = xp[(132 - cc) & 127];                                          \
        v1_ = xp[(131 - cc) & 127];                                          \
        ad_ = ch * CHSZ + rr * NCC + cc;                                     \
    }

__global__ __launch_bounds__(512, 4)
void optical_conv_69698729279498(const float* __restrict__ x,
                                 const float* __restrict__ kern,
                                 float* __restrict__ out) {
    __shared__ __align__(16) unsigned short ldsb[16 * CHSZ];  // 50688 B

    const int tid = threadIdx.x;
    const int l   = tid & 63;
    const int w   = tid >> 6;       // wave 0..7
    const int h   = w & 1;          // phase-half: p' = 4h + pp
    const int oh  = (w >> 1) & 1;   // o-half
    const int rh  = w >> 2;         // row within block's 2-row tile
    const int i0  = blockIdx.x * 2; // first output row of tile
    const int b   = blockIdx.y;     // batch 0..7

    const int lk   = l & 15;        // A m-index / B,D o-index
    const int g    = (l >> 4) & 1;  // tj half for A
    const int hi32 = l >> 5;        // ti parity within chunk for A
    const int g2   = l >> 4;        // quad 0..3
    const int o    = oh * 16 + lk;

    const float* xb = x + ((size_t)b << 18);   // batch slice [16,128,128]

    // ---- staging: issue loads in two register-bounded groups, then pack+store
    float v0a[13], v1a[13]; int aa[13];
#pragma unroll
    for (int k = 0; k < 13; ++k) {
        int s = tid + 512 * k;                 // < 12672 always
        LOAD_SLOT(s, v0a[k], v1a[k], aa[k]);
    }
    float v0b[12], v1b[12]; int ab[12];
#pragma unroll
    for (int k = 0; k < 12; ++k) {
        int s = tid + 512 * (13 + k);
        if (s > NSLOT - 1) s = NSLOT - 1;      // clamped dups write identical data
        LOAD_SLOT(s, v0b[k], v1b[k], ab[k]);
    }
#pragma unroll
    for (int k = 0; k < 13; ++k) {
        unsigned int pk2 = (unsigned int)f2bf(v0a[k]) | ((unsigned int)f2bf(v1a[k]) << 16);
        *(unsigned int*)&ldsb[aa[k]] = pk2;
    }
#pragma unroll
    for (int k = 0; k < 12; ++k) {
        unsigned int pk2 = (unsigned int)f2bf(v0b[k]) | ((unsigned int)f2bf(v1b[k]) << 16);
        *(unsigned int*)&ldsb[ab[k]] = pk2;
    }

    // ---- B fragments: Bk[k=ti*16+tj][o], zeros for ti>8 or tj>8
    // (issued before the barrier; latency overlaps the barrier wait)
    short8 Bf[5];
#pragma unroll
    for (int ck = 0; ck < 5; ++ck) {
        const int ti  = 2 * ck + (g2 >> 1);
        const int tj0 = (g2 & 1) * 8;
        unsigned int pk[4];
#pragma unroll
        for (int ee = 0; ee < 4; ++ee) {
            int tj_a = tj0 + 2 * ee, tj_b = tj_a + 1;
            float va = (ti <= 8 && tj_a <= 8) ? kern[o * 1296 + ti * 9 + tj_a] : 0.f;
            float vb = (ti <= 8 && tj_b <= 8) ? kern[o * 1296 + ti * 9 + tj_b] : 0.f;
            pk[ee] = (unsigned int)f2bf(va) | ((unsigned int)f2bf(vb) << 16);
        }
        uint4v bv; bv.x = pk[0]; bv.y = pk[1]; bv.z = pk[2]; bv.w = pk[3];
        Bf[ck] = __builtin_bit_cast(short8, bv);
    }

    __syncthreads();   // the ONLY barrier in the kernel

    float4v acc[4];
#pragma unroll
    for (int pp = 0; pp < 4; ++pp) acc[pp] = (float4v){0.f, 0.f, 0.f, 0.f};

    for (int c = 0; c < 16; ++c) {
        const unsigned short* lb = ldsb + c * CHSZ;
        float4v D[4];
#pragma unroll
        for (int pp = 0; pp < 4; ++pp) D[pp] = (float4v){0.f, 0.f, 0.f, 0.f};

#pragma unroll
        for (int ck = 0; ck < 5; ++ck) {
            const int ti = 2 * ck + hi32;
            const int r  = 9 - ti + rh;        // staged row for this wave's output row
            // 32 B window: 16 taps for this (row, ti), 16B-aligned
            const char* base = (const char*)lb + (r * 288 + 240 - 16 * lk + 16 * g);
            uint4v w0 = *(const uint4v*)base;
            uint4v w1 = *(const uint4v*)(base + 16);
            unsigned int wnd[8] = {w0.x, w0.y, w0.z, w0.w, w1.x, w1.y, w1.z, w1.w};
            if (h == 0) {               // phases 0..3 -> byte offsets 14,12,10,8
                MFMA_PHASE(3, 1, Bf[ck], D[0]);
                MFMA_PHASE(3, 0, Bf[ck], D[1]);
                MFMA_PHASE(2, 1, Bf[ck], D[2]);
                MFMA_PHASE(2, 0, Bf[ck], D[3]);
            } else {                    // phases 4..7 -> byte offsets 6,4,2,0
                MFMA_PHASE(1, 1, Bf[ck], D[0]);
                MFMA_PHASE(1, 0, Bf[ck], D[1]);
                MFMA_PHASE(0, 1, Bf[ck], D[2]);
                MFMA_PHASE(0, 0, Bf[ck], D[3]);
            }
        }
#pragma unroll
        for (int pp = 0; pp < 4; ++pp)
#pragma unroll
            for (int e = 0; e < 4; ++e) acc[pp][e] += fabsf(D[pp][e]);
    }

    // ---- epilogue: lane holds o = oh*16+lk, row i0+rh, pixels j = 32*g2 + 8*e + p'
    const int i = i0 + rh;
    float* ob = out + ((((size_t)(b * 32 + o)) * 128 + i) << 7);
#pragma unroll
    for (int pp = 0; pp < 4; ++pp) {
        const int pprime = 4 * h + pp;
#pragma unroll
        for (int e = 0; e < 4; ++e)
            ob[32 * g2 + 8 * e + pprime] = acc[pp][e];
    }
}

extern "C" void kernel_launch(void* const* d_in, const int* in_sizes, int n_in,
                              void* d_out, int out_size, void* d_ws, size_t ws_size,
                              hipStream_t stream) {
    const float* x = (const float*)d_in[0];      // [8,16,128,128]
    const float* kern = (const float*)d_in[1];   // [32,16,9,9]
    float* out = (float*)d_out;                  // [8,32,128,128]
    dim3 block(512);
    dim3 grid(64, 8);   // 2 output rows per block x 8 batches = 512 blocks (2/CU)
    hipLaunchKernelGGL(optical_conv_69698729279498, grid, block, 0, stream,
                       x, kern, out);
}